// Round 5
// baseline (215.628 us; speedup 1.0000x reference)
//
#include <hip/hip_runtime.h>

// Problem constants
#define Jd   128   // feature dim
#define Cn   512   // num classes
#define TLn  16    // label seq length
#define Bn   32    // batch

// ---------------------------------------------------------------------------
// Reduction (x, lens dead; batch-uniform trajectory):
//   PLT[tau][j][c] = (L[c,tau,:] @ W)[j]        (transposed for uniform A-reads)
//   LT [tau][j][c] = L[c,tau,j]                 (transposed for coalesced B-reads)
//   l2T[tau][c]    = ||L[c,tau,:]||^2
//   S0[c]          = ||sos@W - L[c,0,:]||^2
//   DOT[s][tau][c] = l2T[tau][c] - 2 * sum_j PLT[tau][j][s]*LT[tau][j][c]
//   s_0 = argmin S0;  s_t = argmin_c sum_{tau<t} DOT[s_{t-1}][tau][c]
//     (p2 and 1/(J*t) are c-constant -> argmin-invariant; values may be
//      NEGATIVE now -> use sign-flip total-order transform for packed keys)
//   out = [ broadcast_B(s_16) | broadcast_B(PLT[:, :, s_15]) ]
// Cumsum pass eliminated: the 1-block chain sums its own <=16 rows per step.
// 3 dispatches total (round-4 had 5 + a 33MB cumsum round-trip + 8-way LDS
// write conflicts in k_dot; this version uses NO LDS tiles in the GEMM).
// ---------------------------------------------------------------------------

__device__ __forceinline__ unsigned int f2ord(float f) {
    unsigned int u = __float_as_uint(f);
    return (u & 0x80000000u) ? ~u : (u | 0x80000000u);   // monotone total order
}
__device__ __forceinline__ unsigned long long packkey(float v, int c) {
    return ((unsigned long long)f2ord(v) << 32) | (unsigned int)c;
}

// grid = 1024 x 128: block g -> tau = g&15, c0 = (g>>4)*8.
// Produces LT, l2T, PLT for its 8 classes at its tau.
__global__ void k_prep(const float* __restrict__ L, const float* __restrict__ W,
                       float* __restrict__ PLT, float* __restrict__ LT,
                       float* __restrict__ l2T) {
    int j = threadIdx.x;                       // 0..127
    int g = blockIdx.x;
    int tau = g & 15, c0 = (g >> 4) * 8;

    // --- transpose + l2: per-lane coalesced row loads ---
    float Lrow[8];
    #pragma unroll
    for (int i = 0; i < 8; ++i)
        Lrow[i] = L[((size_t)(c0 + i) * TLn + tau) * Jd + j];

    float* ltp = LT + ((size_t)tau * Jd + j) * Cn + c0;
    float4 lt0 = {Lrow[0], Lrow[1], Lrow[2], Lrow[3]};
    float4 lt1 = {Lrow[4], Lrow[5], Lrow[6], Lrow[7]};
    *(float4*)ltp = lt0;  *(float4*)(ltp + 4) = lt1;

    __shared__ float red[2][8];
    int w = j >> 6, lane = j & 63;
    #pragma unroll
    for (int i = 0; i < 8; ++i) {
        float p = Lrow[i] * Lrow[i];
        for (int o = 32; o; o >>= 1) p += __shfl_down(p, o, 64);
        if (lane == 0) red[w][i] = p;
    }
    __syncthreads();
    if (j < 8) l2T[(size_t)tau * Cn + c0 + j] = red[0][j] + red[1][j];

    // --- PL rows: acc[i] = sum_k L[c0+i,tau,k] * W[k,j] (uniform L, coalesced W)
    float acc[8];
    #pragma unroll
    for (int i = 0; i < 8; ++i) acc[i] = 0.f;
    const float* Lb = L + ((size_t)c0 * TLn + tau) * Jd;
    for (int k = 0; k < Jd; ++k) {
        float wv = W[k * Jd + j];
        #pragma unroll
        for (int i = 0; i < 8; ++i)
            acc[i] = fmaf(Lb[(size_t)i * TLn * Jd + k], wv, acc[i]);
    }
    float* plp = PLT + ((size_t)tau * Jd + j) * Cn + c0;
    float4 a0 = {acc[0], acc[1], acc[2], acc[3]};
    float4 a1 = {acc[4], acc[5], acc[6], acc[7]};
    *(float4*)plp = a0;  *(float4*)(plp + 4) = a1;
}

// grid = 513 x 256. bid<512: tau = bid>>5, s-tile = (bid&31)*16; computes
// DOT[s][tau][:] for 16 s x 512 c. bid==512: S0.
__global__ void k_dot(const float* __restrict__ LT, const float* __restrict__ PLT,
                      const float* __restrict__ l2T,
                      const float* __restrict__ sos, const float* __restrict__ W,
                      float* __restrict__ DOT, float* __restrict__ S0) {
    int tid = threadIdx.x, bid = blockIdx.x;

    if (bid == 512) {                           // ---- S0 path ----
        __shared__ float pred0[Jd];
        if (tid < Jd) {
            float a = 0.f;
            for (int k = 0; k < Jd; ++k) a = fmaf(sos[k], W[k * Jd + tid], a);
            pred0[tid] = a;
        }
        __syncthreads();
        float a0 = 0.f, a1 = 0.f;
        for (int jj = 0; jj < Jd; ++jj) {
            float p = pred0[jj];
            float d0 = p - LT[(size_t)jj * Cn + tid];         // tau = 0 plane
            float d1 = p - LT[(size_t)jj * Cn + tid + 256];
            a0 = fmaf(d0, d0, a0);
            a1 = fmaf(d1, d1, a1);
        }
        S0[tid] = a0;  S0[tid + 256] = a1;
        return;
    }

    int tau = bid >> 5, s0 = (bid & 31) * 16;
    int h = tid >> 7, cg = tid & 127;           // h: s-half (wave-uniform), cg: 4-c group
    const float* Bp = LT  + (size_t)tau * Jd * Cn + cg * 4;
    const float* Ap = PLT + (size_t)tau * Jd * Cn + s0 + h * 8;

    float acc[8][4];
    #pragma unroll
    for (int i = 0; i < 8; ++i)
        #pragma unroll
        for (int q = 0; q < 4; ++q) acc[i][q] = 0.f;

    #pragma unroll 4
    for (int jj = 0; jj < Jd; ++jj) {
        float4 b  = *(const float4*)(Bp + (size_t)jj * Cn);        // coalesced
        float4 a0 = *(const float4*)(Ap + (size_t)jj * Cn);        // wave-uniform
        float4 a1 = *(const float4*)(Ap + (size_t)jj * Cn + 4);
        float av[8] = {a0.x, a0.y, a0.z, a0.w, a1.x, a1.y, a1.z, a1.w};
        #pragma unroll
        for (int i = 0; i < 8; ++i) {
            acc[i][0] = fmaf(av[i], b.x, acc[i][0]);
            acc[i][1] = fmaf(av[i], b.y, acc[i][1]);
            acc[i][2] = fmaf(av[i], b.z, acc[i][2]);
            acc[i][3] = fmaf(av[i], b.w, acc[i][3]);
        }
    }

    float4 l2v = *(const float4*)(l2T + (size_t)tau * Cn + cg * 4);
    #pragma unroll
    for (int i = 0; i < 8; ++i) {
        int s = s0 + h * 8 + i;
        float4 v = {l2v.x - 2.f * acc[i][0], l2v.y - 2.f * acc[i][1],
                    l2v.z - 2.f * acc[i][2], l2v.w - 2.f * acc[i][3]};
        *(float4*)(DOT + ((size_t)s * TLn + tau) * Cn + cg * 4) = v;
    }
}

// 1 block x 256: 17-step argmin chain + output write (no separate k_out).
__global__ void k_seq(const float* __restrict__ S0, const float* __restrict__ DOT,
                      const float* __restrict__ PLT, float* __restrict__ out) {
    __shared__ unsigned long long red[4];
    __shared__ int sCur;
    __shared__ int keys[TLn + 1];
    int tid = threadIdx.x, w = tid >> 6, lane = tid & 63;

    for (int t = 0; t <= TLn; ++t) {
        float sum0, sum1;
        if (t == 0) {
            sum0 = S0[tid];  sum1 = S0[tid + 256];
        } else {
            sum0 = sum1 = 0.f;
            const float* base = DOT + (size_t)sCur * TLn * Cn;
            for (int tau = 0; tau < t; ++tau) {            // independent loads
                sum0 += base[(size_t)tau * Cn + tid];
                sum1 += base[(size_t)tau * Cn + tid + 256];
            }
        }
        unsigned long long m0 = packkey(sum0, tid);
        unsigned long long m1 = packkey(sum1, tid + 256);
        unsigned long long m = (m1 < m0) ? m1 : m0;
        for (int o = 32; o; o >>= 1) {
            unsigned long long o2 = __shfl_down(m, o, 64);
            if (o2 < m) m = o2;
        }
        if (lane == 0) red[w] = m;
        __syncthreads();
        if (tid == 0) {
            unsigned long long b = red[0];
            #pragma unroll
            for (int i = 1; i < 4; ++i) if (red[i] < b) b = red[i];
            int s = (int)(b & 0xFFFFFFFFull);
            sCur = s;  keys[t] = s;
        }
        __syncthreads();
    }

    int s16 = keys[TLn], s15 = keys[TLn - 1];
    const int total = Bn + Bn * TLn * Jd;                   // 65568
    for (int i = tid; i < total; i += 256) {
        if (i < Bn) {
            out[i] = (float)s16;
        } else {
            int pos = (i - Bn) & (TLn * Jd - 1);            // tau*Jd + j
            out[i] = PLT[(size_t)pos * Cn + s15];           // L1-hot after first b
        }
    }
}

extern "C" void kernel_launch(void* const* d_in, const int* in_sizes, int n_in,
                              void* d_out, int out_size, void* d_ws, size_t ws_size,
                              hipStream_t stream) {
    // inputs: 0:x (dead, 32MB), 1:lens (dead), 2:sos, 3:label_seqs, 4:W  (all f32)
    const float* sos = (const float*)d_in[2];
    const float* L   = (const float*)d_in[3];
    const float* W   = (const float*)d_in[4];
    float* out = (float*)d_out;

    // ws layout: S0(2KB)@0 | l2T(32KB)@4K | PLT(4MB)@64K | LT(4MB) | DOT(16.8MB)
    const size_t l2Off  = 4096;
    const size_t pltOff = 65536;
    const size_t ltOff  = pltOff + (size_t)TLn * Jd * Cn * sizeof(float);
    const size_t dotOff = ltOff  + (size_t)TLn * Jd * Cn * sizeof(float);
    const size_t need   = dotOff + (size_t)Cn * TLn * Cn * sizeof(float);  // ~25 MB
    char* base = (ws_size >= need) ? (char*)d_ws : (char*)d_in[0];  // x dead, 32 MB
    float* S0  = (float*)base;
    float* l2T = (float*)(base + l2Off);
    float* PLT = (float*)(base + pltOff);
    float* LT  = (float*)(base + ltOff);
    float* DOT = (float*)(base + dotOff);

    hipLaunchKernelGGL(k_prep, dim3(1024), dim3(Jd), 0, stream, L, W, PLT, LT, l2T);
    hipLaunchKernelGGL(k_dot, dim3(513), dim3(256), 0, stream,
                       LT, PLT, l2T, sos, W, DOT, S0);
    hipLaunchKernelGGL(k_seq, dim3(1), dim3(256), 0, stream, S0, DOT, PLT, out);
}

// Round 6
// 158.183 us; speedup vs baseline: 1.3632x; 1.3632x over previous
//
#include <hip/hip_runtime.h>

// Problem constants
#define Jd   128   // feature dim
#define Cn   512   // num classes
#define TLn  16    // label seq length
#define Bn   32    // batch

// ---------------------------------------------------------------------------
// Reduction (x, lens dead; batch-uniform trajectory):
//   PLT[tau][j][c] = (L[c,tau,:] @ W)[j]        (transposed for uniform A-reads)
//   LT [tau][j][c] = L[c,tau,j]                 (transposed for coalesced B-reads)
//   l2T[tau][c]    = ||L[c,tau,:]||^2
//   S0[c]          = ||sos@W - L[c,0,:]||^2
//   DOT[s][tau][c] = l2T[tau][c] - 2 * sum_j PLT[tau][j][s]*LT[tau][j][c]
//   s_0 = argmin S0;  s_t = argmin_c sum_{tau<t} DOT[s_{t-1}][tau][c]
//     (p2 and 1/(J*t) are c-constant -> argmin-invariant; DOT may be negative
//      -> sign-flip total-order transform for packed argmin keys)
//   out = [ broadcast_B(s_16) | broadcast_B(PLT[:, :, s_15]) ]
// Round-5 lesson: the 1-block chain was latency-serialized (runtime-bound tau
// loop -> one vmcnt(0) per load; fused output write -> 256 more round-trips).
// Fix: fixed-bound unroll-16 masked loads (all rows in flight at once) and a
// wide separate k_out. k_prep/k_dot unchanged for clean attribution.
// ---------------------------------------------------------------------------

__device__ __forceinline__ unsigned int f2ord(float f) {
    unsigned int u = __float_as_uint(f);
    return (u & 0x80000000u) ? ~u : (u | 0x80000000u);   // monotone total order
}
__device__ __forceinline__ unsigned long long packkey(float v, int c) {
    return ((unsigned long long)f2ord(v) << 32) | (unsigned int)c;
}

// grid = 1024 x 128: block g -> tau = g&15, c0 = (g>>4)*8.
__global__ void k_prep(const float* __restrict__ L, const float* __restrict__ W,
                       float* __restrict__ PLT, float* __restrict__ LT,
                       float* __restrict__ l2T) {
    int j = threadIdx.x;                       // 0..127
    int g = blockIdx.x;
    int tau = g & 15, c0 = (g >> 4) * 8;

    // --- transpose + l2: per-lane coalesced row loads ---
    float Lrow[8];
    #pragma unroll
    for (int i = 0; i < 8; ++i)
        Lrow[i] = L[((size_t)(c0 + i) * TLn + tau) * Jd + j];

    float* ltp = LT + ((size_t)tau * Jd + j) * Cn + c0;
    float4 lt0 = {Lrow[0], Lrow[1], Lrow[2], Lrow[3]};
    float4 lt1 = {Lrow[4], Lrow[5], Lrow[6], Lrow[7]};
    *(float4*)ltp = lt0;  *(float4*)(ltp + 4) = lt1;

    __shared__ float red[2][8];
    int w = j >> 6, lane = j & 63;
    #pragma unroll
    for (int i = 0; i < 8; ++i) {
        float p = Lrow[i] * Lrow[i];
        for (int o = 32; o; o >>= 1) p += __shfl_down(p, o, 64);
        if (lane == 0) red[w][i] = p;
    }
    __syncthreads();
    if (j < 8) l2T[(size_t)tau * Cn + c0 + j] = red[0][j] + red[1][j];

    // --- PL rows: acc[i] = sum_k L[c0+i,tau,k] * W[k,j]
    // (uniform float4 L loads, 4x fewer scalar-load round-trips; coalesced W)
    float acc[8];
    #pragma unroll
    for (int i = 0; i < 8; ++i) acc[i] = 0.f;
    const float4* Lb4 = (const float4*)(L + ((size_t)c0 * TLn + tau) * Jd);
    for (int k4 = 0; k4 < Jd / 4; ++k4) {
        float4 lv[8];
        #pragma unroll
        for (int i = 0; i < 8; ++i) lv[i] = Lb4[(size_t)i * (TLn * Jd / 4) + k4];
        #pragma unroll
        for (int u = 0; u < 4; ++u) {
            float wv = W[(k4 * 4 + u) * Jd + j];
            #pragma unroll
            for (int i = 0; i < 8; ++i) {
                float lvu = (u == 0) ? lv[i].x : (u == 1) ? lv[i].y
                          : (u == 2) ? lv[i].z : lv[i].w;
                acc[i] = fmaf(lvu, wv, acc[i]);
            }
        }
    }
    float* plp = PLT + ((size_t)tau * Jd + j) * Cn + c0;
    float4 a0 = {acc[0], acc[1], acc[2], acc[3]};
    float4 a1 = {acc[4], acc[5], acc[6], acc[7]};
    *(float4*)plp = a0;  *(float4*)(plp + 4) = a1;
}

// grid = 513 x 256. bid<512: tau = bid>>5, s-tile = (bid&31)*16.
__global__ void k_dot(const float* __restrict__ LT, const float* __restrict__ PLT,
                      const float* __restrict__ l2T,
                      const float* __restrict__ sos, const float* __restrict__ W,
                      float* __restrict__ DOT, float* __restrict__ S0) {
    int tid = threadIdx.x, bid = blockIdx.x;

    if (bid == 512) {                           // ---- S0 path ----
        __shared__ float pred0[Jd];
        if (tid < Jd) {
            float a = 0.f;
            for (int k = 0; k < Jd; ++k) a = fmaf(sos[k], W[k * Jd + tid], a);
            pred0[tid] = a;
        }
        __syncthreads();
        float a0 = 0.f, a1 = 0.f;
        for (int jj = 0; jj < Jd; ++jj) {
            float p = pred0[jj];
            float d0 = p - LT[(size_t)jj * Cn + tid];         // tau = 0 plane
            float d1 = p - LT[(size_t)jj * Cn + tid + 256];
            a0 = fmaf(d0, d0, a0);
            a1 = fmaf(d1, d1, a1);
        }
        S0[tid] = a0;  S0[tid + 256] = a1;
        return;
    }

    int tau = bid >> 5, s0 = (bid & 31) * 16;
    int h = tid >> 7, cg = tid & 127;           // h: s-half (wave-uniform), cg: 4-c group
    const float* Bp = LT  + (size_t)tau * Jd * Cn + cg * 4;
    const float* Ap = PLT + (size_t)tau * Jd * Cn + s0 + h * 8;

    float acc[8][4];
    #pragma unroll
    for (int i = 0; i < 8; ++i)
        #pragma unroll
        for (int q = 0; q < 4; ++q) acc[i][q] = 0.f;

    #pragma unroll 4
    for (int jj = 0; jj < Jd; ++jj) {
        float4 b  = *(const float4*)(Bp + (size_t)jj * Cn);        // coalesced
        float4 a0 = *(const float4*)(Ap + (size_t)jj * Cn);        // wave-uniform
        float4 a1 = *(const float4*)(Ap + (size_t)jj * Cn + 4);
        float av[8] = {a0.x, a0.y, a0.z, a0.w, a1.x, a1.y, a1.z, a1.w};
        #pragma unroll
        for (int i = 0; i < 8; ++i) {
            acc[i][0] = fmaf(av[i], b.x, acc[i][0]);
            acc[i][1] = fmaf(av[i], b.y, acc[i][1]);
            acc[i][2] = fmaf(av[i], b.z, acc[i][2]);
            acc[i][3] = fmaf(av[i], b.w, acc[i][3]);
        }
    }

    float4 l2v = *(const float4*)(l2T + (size_t)tau * Cn + cg * 4);
    #pragma unroll
    for (int i = 0; i < 8; ++i) {
        int s = s0 + h * 8 + i;
        float4 v = {l2v.x - 2.f * acc[i][0], l2v.y - 2.f * acc[i][1],
                    l2v.z - 2.f * acc[i][2], l2v.w - 2.f * acc[i][3]};
        *(float4*)(DOT + ((size_t)s * TLn + tau) * Cn + cg * 4) = v;
    }
}

// 1 block x 256: 17-step argmin chain. All 16 tau-rows loaded unconditionally
// (fixed bound -> full unroll -> 32 loads in flight, ONE latency per step),
// masked by (tau < t) FMA. Writes keys to global for k_out.
__global__ void k_seq(const float* __restrict__ S0, const float* __restrict__ DOT,
                      int* __restrict__ keys) {
    __shared__ unsigned long long red[4];
    __shared__ int sCur;
    int tid = threadIdx.x, w = tid >> 6, lane = tid & 63;

    for (int t = 0; t <= TLn; ++t) {
        float sum0, sum1;
        if (t == 0) {
            sum0 = S0[tid];  sum1 = S0[tid + 256];
        } else {
            const float* base = DOT + (size_t)sCur * TLn * Cn;
            float v0[TLn], v1[TLn];
            #pragma unroll
            for (int tau = 0; tau < TLn; ++tau) {              // 32 independent loads
                v0[tau] = base[(size_t)tau * Cn + tid];
                v1[tau] = base[(size_t)tau * Cn + tid + 256];
            }
            sum0 = sum1 = 0.f;
            #pragma unroll
            for (int tau = 0; tau < TLn; ++tau) {
                float m = (tau < t) ? 1.f : 0.f;
                sum0 = fmaf(v0[tau], m, sum0);
                sum1 = fmaf(v1[tau], m, sum1);
            }
        }
        unsigned long long m0 = packkey(sum0, tid);
        unsigned long long m1 = packkey(sum1, tid + 256);
        unsigned long long m = (m1 < m0) ? m1 : m0;
        for (int o = 32; o; o >>= 1) {
            unsigned long long o2 = __shfl_down(m, o, 64);
            if (o2 < m) m = o2;
        }
        if (lane == 0) red[w] = m;
        __syncthreads();
        if (tid == 0) {
            unsigned long long b = red[0];
            #pragma unroll
            for (int i = 1; i < 4; ++i) if (red[i] < b) b = red[i];
            int s = (int)(b & 0xFFFFFFFFull);
            sCur = s;  keys[t] = s;
        }
        __syncthreads();
    }
}

// grid = 512 x 128: out = [sofar(32) | pls(B,TL,J)]
__global__ void k_out(const float* __restrict__ PLT, const int* __restrict__ keys,
                      float* __restrict__ out) {
    int bt = blockIdx.x, j = threadIdx.x, tau = bt & (TLn - 1);
    int s16 = keys[TLn], s15 = keys[TLn - 1];
    out[Bn + (size_t)bt * Jd + j] = PLT[((size_t)tau * Jd + j) * Cn + s15];  // L2-hot
    if (bt == 0 && j < Bn) out[j] = (float)s16;
}

extern "C" void kernel_launch(void* const* d_in, const int* in_sizes, int n_in,
                              void* d_out, int out_size, void* d_ws, size_t ws_size,
                              hipStream_t stream) {
    // inputs: 0:x (dead, 32MB), 1:lens (dead), 2:sos, 3:label_seqs, 4:W  (all f32)
    const float* sos = (const float*)d_in[2];
    const float* L   = (const float*)d_in[3];
    const float* W   = (const float*)d_in[4];
    float* out = (float*)d_out;

    // ws layout: S0(2KB)@0 | keys@2048 | l2T(32KB)@4K | PLT(4MB)@64K | LT(4MB) | DOT(16.8MB)
    const size_t l2Off  = 4096;
    const size_t pltOff = 65536;
    const size_t ltOff  = pltOff + (size_t)TLn * Jd * Cn * sizeof(float);
    const size_t dotOff = ltOff  + (size_t)TLn * Jd * Cn * sizeof(float);
    const size_t need   = dotOff + (size_t)Cn * TLn * Cn * sizeof(float);  // ~25 MB
    char* base = (ws_size >= need) ? (char*)d_ws : (char*)d_in[0];  // x dead, 32 MB
    float* S0   = (float*)base;
    int*   keys = (int*)(base + 2048);
    float* l2T  = (float*)(base + l2Off);
    float* PLT  = (float*)(base + pltOff);
    float* LT   = (float*)(base + ltOff);
    float* DOT  = (float*)(base + dotOff);

    hipLaunchKernelGGL(k_prep, dim3(1024), dim3(Jd), 0, stream, L, W, PLT, LT, l2T);
    hipLaunchKernelGGL(k_dot, dim3(513), dim3(256), 0, stream,
                       LT, PLT, l2T, sos, W, DOT, S0);
    hipLaunchKernelGGL(k_seq, dim3(1), dim3(256), 0, stream, S0, DOT, keys);
    hipLaunchKernelGGL(k_out, dim3(Bn * TLn), dim3(Jd), 0, stream, PLT, keys, out);
}

// Round 7
// 146.154 us; speedup vs baseline: 1.4753x; 1.0823x over previous
//
#include <hip/hip_runtime.h>

// Problem constants
#define Jd   128   // feature dim
#define Cn   512   // num classes
#define TLn  16    // label seq length
#define Bn   32    // batch

// ---------------------------------------------------------------------------
// Reduction (x, lens dead; batch-uniform trajectory):
//   LT [tau][k][c] = L[c,tau,k]                 (coalesced-B layout)
//   l2T[tau][c]    = ||L[c,tau,:]||^2
//   PLT[tau][j][c] = sum_k W[k][j] * LT[tau][k][c]   ( = (L@W)^T )
//   S0[c]          = ||sos@W - L[c,0,:]||^2
//   DOT[s][tau][c] = l2T[tau][c] - 2 * sum_j PLT[tau][j][s]*LT[tau][j][c]
//   s_0 = argmin S0;  s_t = argmin_c sum_{tau<t} DOT[s_{t-1}][tau][c]
//   out = [ broadcast_B(s_16) | broadcast_B(PLT[:, :, s_15]) ]
// Round-6 lessons: (a) k_dot was latency-bound at 8 waves/CU (VALUBusy 15%,
// occ 18%) -> regrid to 1024 blocks / 16 waves/CU, 32-s tiles halve B traffic;
// (b) k_prep's 2KB-stride stores (64 scattered 16B writes/wave) cost ~25us ->
// replaced by LDS-tiled k_tr + GEMM-shaped k_plt, all stores coalesced.
// ---------------------------------------------------------------------------

__device__ __forceinline__ unsigned int f2ord(float f) {
    unsigned int u = __float_as_uint(f);
    return (u & 0x80000000u) ? ~u : (u | 0x80000000u);   // monotone total order
}
__device__ __forceinline__ unsigned long long packkey(float v, int c) {
    return ((unsigned long long)f2ord(v) << 32) | (unsigned int)c;
}

// grid = 256 x 256: bid -> tau = bid&15, c0 = (bid>>4)*32.
// Stage 32 L-rows in LDS (coalesced reads), emit LT in 128B-contiguous chunks
// (vs round-6's 64 scattered 16B writes per wave). l2 fused via quad shuffles.
__global__ void k_tr(const float* __restrict__ L, float* __restrict__ LT,
                     float* __restrict__ l2T) {
    __shared__ float Ls[32][132];                // +4 pad (16B-aligned rows)
    int tid = threadIdx.x, bid = blockIdx.x;
    int tau = bid & 15, c0 = (bid >> 4) * 32;
    int r = tid >> 3, o = tid & 7;               // row 0..31, octant
    const float4* src = (const float4*)(L + ((size_t)(c0 + r) * TLn + tau) * Jd);
    float l2p = 0.f;
    #pragma unroll
    for (int i = 0; i < 4; ++i) {
        float4 v = src[o * 4 + i];
        *(float4*)&Ls[r][(o * 4 + i) * 4] = v;
        l2p += v.x * v.x + v.y * v.y + v.z * v.z + v.w * v.w;
    }
    l2p += __shfl_xor(l2p, 1, 64);
    l2p += __shfl_xor(l2p, 2, 64);
    l2p += __shfl_xor(l2p, 4, 64);
    if (o == 0) l2T[tau * Cn + c0 + r] = l2p;
    __syncthreads();
    int cc = tid & 31, jg = tid >> 5;            // lane->c (coalesced), 8 j-groups
    #pragma unroll
    for (int j = jg; j < Jd; j += 8)
        LT[((size_t)tau * Jd + j) * Cn + c0 + cc] = Ls[cc][j];
}

// grid = 256 x 256: tau = bid&15, jt = (bid>>4)&3, cq = bid>>6.
// PLT[tau][j][c] = sum_k W[k][j] * LT[tau][k][c]. A uniform, B+D coalesced.
__global__ void k_plt(const float* __restrict__ W, const float* __restrict__ LT,
                      float* __restrict__ PLT) {
    int tid = threadIdx.x, bid = blockIdx.x;
    int tau = bid & 15, jt = (bid >> 4) & 3, cq = bid >> 6;
    int cg = tid & 31, jh = tid >> 5;
    int c = cq * 128 + cg * 4, j = jt * 32 + jh * 4;
    const float* Bp = LT + (size_t)tau * Jd * Cn + c;
    const float* Ap = W + j;
    float acc[4][4] = {};
    #pragma unroll 8
    for (int k = 0; k < Jd; ++k) {
        float4 a = *(const float4*)(Ap + (size_t)k * Jd);   // half-wave uniform
        float4 b = *(const float4*)(Bp + (size_t)k * Cn);   // coalesced
        float av[4] = {a.x, a.y, a.z, a.w};
        #pragma unroll
        for (int i = 0; i < 4; ++i) {
            acc[i][0] = fmaf(av[i], b.x, acc[i][0]);
            acc[i][1] = fmaf(av[i], b.y, acc[i][1]);
            acc[i][2] = fmaf(av[i], b.z, acc[i][2]);
            acc[i][3] = fmaf(av[i], b.w, acc[i][3]);
        }
    }
    float* dst = PLT + ((size_t)tau * Jd + j) * Cn + c;
    #pragma unroll
    for (int i = 0; i < 4; ++i) {
        float4 v = {acc[i][0], acc[i][1], acc[i][2], acc[i][3]};
        *(float4*)(dst + (size_t)i * Cn) = v;               // coalesced
    }
}

// grid = 1025 x 256. bid<1024: tau = bid&15, st = (bid>>4)&15, cq = bid>>8;
// 32 s x 128 c per block (4 blocks/CU -> 16 waves/CU). bid==1024: S0.
__global__ void k_dot(const float* __restrict__ LT, const float* __restrict__ PLT,
                      const float* __restrict__ l2T,
                      const float* __restrict__ sos, const float* __restrict__ W,
                      float* __restrict__ DOT, float* __restrict__ S0) {
    int tid = threadIdx.x, bid = blockIdx.x;

    if (bid == 1024) {                           // ---- S0 path ----
        __shared__ float pred0[Jd];
        if (tid < Jd) {
            float a = 0.f;
            for (int k = 0; k < Jd; ++k) a = fmaf(sos[k], W[k * Jd + tid], a);
            pred0[tid] = a;
        }
        __syncthreads();
        float a0 = 0.f, a1 = 0.f;
        for (int jj = 0; jj < Jd; ++jj) {
            float p = pred0[jj];
            float d0 = p - LT[(size_t)jj * Cn + tid];        // tau = 0 plane
            float d1 = p - LT[(size_t)jj * Cn + tid + 256];
            a0 = fmaf(d0, d0, a0);
            a1 = fmaf(d1, d1, a1);
        }
        S0[tid] = a0;  S0[tid + 256] = a1;
        return;
    }

    int tau = bid & 15, st = (bid >> 4) & 15, cq = bid >> 8;
    int cg = tid & 31, sh = tid >> 5;
    int c = cq * 128 + cg * 4, s = st * 32 + sh * 4;
    const float* Bp = LT  + (size_t)tau * Jd * Cn + c;
    const float* Ap = PLT + (size_t)tau * Jd * Cn + s;
    float acc[4][4] = {};
    #pragma unroll 8
    for (int jj = 0; jj < Jd; ++jj) {
        float4 a = *(const float4*)(Ap + (size_t)jj * Cn);  // half-wave uniform
        float4 b = *(const float4*)(Bp + (size_t)jj * Cn);  // coalesced
        float av[4] = {a.x, a.y, a.z, a.w};
        #pragma unroll
        for (int i = 0; i < 4; ++i) {
            acc[i][0] = fmaf(av[i], b.x, acc[i][0]);
            acc[i][1] = fmaf(av[i], b.y, acc[i][1]);
            acc[i][2] = fmaf(av[i], b.z, acc[i][2]);
            acc[i][3] = fmaf(av[i], b.w, acc[i][3]);
        }
    }
    float4 l2v = *(const float4*)(l2T + tau * Cn + c);
    #pragma unroll
    for (int i = 0; i < 4; ++i) {
        float4 v = {l2v.x - 2.f * acc[i][0], l2v.y - 2.f * acc[i][1],
                    l2v.z - 2.f * acc[i][2], l2v.w - 2.f * acc[i][3]};
        *(float4*)(DOT + ((size_t)(s + i) * TLn + tau) * Cn + c) = v;  // coalesced
    }
}

// 1 block x 256: 17-step argmin chain, fixed-bound unroll (32 loads in flight
// per step, ONE latency round-trip), mask-FMA for tau<t.
__global__ void k_seq(const float* __restrict__ S0, const float* __restrict__ DOT,
                      int* __restrict__ keys) {
    __shared__ unsigned long long red[4];
    __shared__ int sCur;
    int tid = threadIdx.x, w = tid >> 6, lane = tid & 63;

    for (int t = 0; t <= TLn; ++t) {
        float sum0, sum1;
        if (t == 0) {
            sum0 = S0[tid];  sum1 = S0[tid + 256];
        } else {
            const float* base = DOT + (size_t)sCur * TLn * Cn;
            float v0[TLn], v1[TLn];
            #pragma unroll
            for (int tau = 0; tau < TLn; ++tau) {
                v0[tau] = base[(size_t)tau * Cn + tid];
                v1[tau] = base[(size_t)tau * Cn + tid + 256];
            }
            sum0 = sum1 = 0.f;
            #pragma unroll
            for (int tau = 0; tau < TLn; ++tau) {
                float m = (tau < t) ? 1.f : 0.f;
                sum0 = fmaf(v0[tau], m, sum0);
                sum1 = fmaf(v1[tau], m, sum1);
            }
        }
        unsigned long long m0 = packkey(sum0, tid);
        unsigned long long m1 = packkey(sum1, tid + 256);
        unsigned long long m = (m1 < m0) ? m1 : m0;
        for (int o = 32; o; o >>= 1) {
            unsigned long long o2 = __shfl_down(m, o, 64);
            if (o2 < m) m = o2;
        }
        if (lane == 0) red[w] = m;
        __syncthreads();
        if (tid == 0) {
            unsigned long long b = red[0];
            #pragma unroll
            for (int i = 1; i < 4; ++i) if (red[i] < b) b = red[i];
            int sv = (int)(b & 0xFFFFFFFFull);
            sCur = sv;  keys[t] = sv;
        }
        __syncthreads();
    }
}

// grid = 512 x 128: out = [sofar(32) | pls(B,TL,J)]
__global__ void k_out(const float* __restrict__ PLT, const int* __restrict__ keys,
                      float* __restrict__ out) {
    int bt = blockIdx.x, j = threadIdx.x, tau = bt & (TLn - 1);
    int s16 = keys[TLn], s15 = keys[TLn - 1];
    out[Bn + (size_t)bt * Jd + j] = PLT[((size_t)tau * Jd + j) * Cn + s15];  // L2-hot
    if (bt == 0 && j < Bn) out[j] = (float)s16;
}

extern "C" void kernel_launch(void* const* d_in, const int* in_sizes, int n_in,
                              void* d_out, int out_size, void* d_ws, size_t ws_size,
                              hipStream_t stream) {
    // inputs: 0:x (dead, 32MB), 1:lens (dead), 2:sos, 3:label_seqs, 4:W  (all f32)
    const float* sos = (const float*)d_in[2];
    const float* L   = (const float*)d_in[3];
    const float* W   = (const float*)d_in[4];
    float* out = (float*)d_out;

    // ws: S0(2KB)@0 | keys@2048 | l2T(32KB)@4K | PLT(4MB)@64K | LT(4MB) | DOT(16.8MB)
    const size_t l2Off  = 4096;
    const size_t pltOff = 65536;
    const size_t ltOff  = pltOff + (size_t)TLn * Jd * Cn * sizeof(float);
    const size_t dotOff = ltOff  + (size_t)TLn * Jd * Cn * sizeof(float);
    const size_t need   = dotOff + (size_t)Cn * TLn * Cn * sizeof(float);  // ~25 MB
    char* base = (ws_size >= need) ? (char*)d_ws : (char*)d_in[0];  // x dead, 32 MB
    float* S0   = (float*)base;
    int*   keys = (int*)(base + 2048);
    float* l2T  = (float*)(base + l2Off);
    float* PLT  = (float*)(base + pltOff);
    float* LT   = (float*)(base + ltOff);
    float* DOT  = (float*)(base + dotOff);

    hipLaunchKernelGGL(k_tr,  dim3(256),  dim3(256), 0, stream, L, LT, l2T);
    hipLaunchKernelGGL(k_plt, dim3(256),  dim3(256), 0, stream, W, LT, PLT);
    hipLaunchKernelGGL(k_dot, dim3(1025), dim3(256), 0, stream,
                       LT, PLT, l2T, sos, W, DOT, S0);
    hipLaunchKernelGGL(k_seq, dim3(1),   dim3(256), 0, stream, S0, DOT, keys);
    hipLaunchKernelGGL(k_out, dim3(Bn * TLn), dim3(Jd), 0, stream, PLT, keys, out);
}